// Round 6
// baseline (520.939 us; speedup 1.0000x reference)
//
#include <hip/hip_runtime.h>
#include <hip/hip_bf16.h>
#include <math.h>

// ---------------------------------------------------------------------------
// TransformerDecoderBlock  (B=4, S=2048, E=768, DFF=3072)
// Round 12: 128x128 tile / BK=64 / 8 waves / 64 KiB LDS -> 2 blocks per CU.
// Rationale: all GEMMs here have short K (NI=6..12); the 256^2 kernel's
// 128 KiB LDS + 128-VGPR acc capped the CU at 1 block / 2 waves-per-SIMD, so
// per-block fixed costs (prologue latency, epilogue, barrier skew, tails)
// were unhidden (3 rounds of schedule surgery: 34% MfmaUtil plateau).
// 2 co-resident blocks overlap one block's stalls with the other's MFMA.
// Core keeps the pipelined phase structure: per phase {6 ds_read prefetch of
// NEXT phase ∥ 8 MFMA}, 2 barriers per 2-tile iteration, async staging via
// global_load_lds with T2 swizzle (slot ^= row&7), setprio around MFMA.
// Epilogue single-pass (stride 136 = 272B rows, 16B-aligned -> uint4 out).
// ---------------------------------------------------------------------------

typedef __bf16 bf16_t;
typedef bf16_t bf16x4 __attribute__((ext_vector_type(4)));
typedef bf16_t bf16x8 __attribute__((ext_vector_type(8)));
typedef float f32x4 __attribute__((ext_vector_type(4)));

struct MMDesc {
    const bf16_t* A;
    const bf16_t* B;
    const float* bias;
    __hip_bfloat16* C;
    float* lsum;
    int koff;
    int trans;  // epilogue writes C transposed into [E][2048-per-batch] layout
};
struct MMArgs { MMDesc g[8]; };

// bijective XCD swizzle (m204): contiguous chunk per XCD, any grid size
__device__ __forceinline__ int xcd_swz(int bid, int nwg) {
    const int q = nwg >> 3, r = nwg & 7;
    const int xcd = bid & 7, o = bid >> 3;
    const int base = (xcd < r) ? xcd * (q + 1) : r * (q + 1) + (xcd - r) * q;
    return base + o;
}

// async global->LDS, 16B per lane. LDS dest = wave-uniform base + lane*16.
__device__ __forceinline__ void load16(const bf16_t* g, bf16_t* l) {
    __builtin_amdgcn_global_load_lds(
        (const __attribute__((address_space(1))) unsigned int*)g,
        (__attribute__((address_space(3))) unsigned int*)l, 16, 0, 0);
}

#define SBAR asm volatile("s_barrier" ::: "memory")
#define SCH  __builtin_amdgcn_sched_barrier(0)
#define PRIO1 __builtin_amdgcn_s_setprio(1)
#define PRIO0 __builtin_amdgcn_s_setprio(0)
#define VMC0 asm volatile("s_waitcnt vmcnt(0)" ::: "memory")

// A prefetch: 4 m-frags (stride 1024 elems)
#define RDA(dst, base) do { \
    _Pragma("unroll") \
    for (int i_ = 0; i_ < 4; ++i_) \
        dst[i_] = *(const bf16x8*)((base) + i_ * 1024); \
} while (0)
// B prefetch: 2 n-frags
#define RDB(dst, base) do { \
    dst[0] = *(const bf16x8*)(base); \
    dst[1] = *(const bf16x8*)((base) + 1024); \
} while (0)
// 8-MFMA cluster: 4 m-frags x 2 n-frags, one k-sub
#define CL8(A_, B_) do { \
    _Pragma("unroll") \
    for (int mi = 0; mi < 4; ++mi) \
    _Pragma("unroll") \
    for (int nj = 0; nj < 2; ++nj) \
        acc[mi][nj] = __builtin_amdgcn_mfma_f32_16x16x32_bf16( \
            A_[mi], B_[nj], acc[mi][nj], 0, 0, 0); \
} while (0)
// phase pin: 6 ds_reads then 8 MFMAs (DS_READ=0x100, MFMA=0x8)
#define PH6 do { \
    __builtin_amdgcn_sched_group_barrier(0x100, 6, 0); \
    __builtin_amdgcn_sched_group_barrier(0x008, 8, 0); \
    SCH; \
} while (0)

// 128x128 tile, BK=64, 8 waves (2m x 4n), double-buffered 64 KiB LDS.
// LDS elems: buf b: A at b*16384, B at b*16384+8192; row r at r*64 with
// 16B-slot swizzle slot ^= (r&7). K multiple of 128.
// Per 2-tile iteration: 4 phases, each {pf next-phase frags ∥ 8 MFMA};
// barrier+vmcnt(0) between phi1/phi2 (certifies buf1 staged, buf0 reads done)
// and phi3/phi4 (certifies buf0(t+2), buf1 reads done). Staging of tile t+2
// at phi2, t+3 at phi4 (post-barrier).
__device__ __forceinline__ void mm8_core(
    const bf16_t* Ag, const bf16_t* Bg, int lda, int ldb, int K,
    bf16_t* lds, int w, int l, f32x4 acc[4][2])
{
    const long ldal = lda, ldbl = ldb;
    const int fr = l & 15, kq = l >> 4;
    // staging: thread t=w*64+l -> row rr (0..63 per half), slot l&7,
    // logical slot (l&7)^(rr&7)
    const int rr = w * 8 + (l >> 3);
    const int c8e = ((l & 7) ^ (l >> 3)) * 8;
    const bf16_t* pA0 = Ag + (long)rr * ldal + c8e;
    const bf16_t* pA1 = pA0 + 64 * ldal;
    const bf16_t* pB0 = Bg + (long)rr * ldbl + c8e;
    const bf16_t* pB1 = pB0 + 64 * ldbl;
    // ds_read swizzled slot offsets for k-sub 0/1 (frag row & 7 == fr&7)
    const int s0 = ((0 + kq) ^ (fr & 7)) * 8;
    const int s1 = ((4 + kq) ^ (fr & 7)) * 8;
    const int arow = ((w >> 2) * 64 + fr) * 64;
    const int brow = ((w & 3) * 32 + fr) * 64;
    const bf16_t* A00 = lds + arow + s0;           // buf0 ks0
    const bf16_t* A01 = lds + arow + s1;           // buf0 ks1
    const bf16_t* A10 = lds + 16384 + arow + s0;   // buf1 ks0
    const bf16_t* A11 = lds + 16384 + arow + s1;
    const bf16_t* B00 = lds + 8192 + brow + s0;
    const bf16_t* B01 = lds + 8192 + brow + s1;
    const bf16_t* B10 = lds + 24576 + brow + s0;
    const bf16_t* B11 = lds + 24576 + brow + s1;
    bf16_t* stA = lds + w * 512;
    bf16_t* stB = lds + 8192 + w * 512;

    auto stg = [&](int b, int t) {  // stage full K-tile t into buf b (4 load16)
        const bf16_t* ga = pA0 + (long)t * 64;
        const bf16_t* gb = pB0 + (long)t * 64;
        bf16_t* da = stA + b * 16384;
        bf16_t* db = stB + b * 16384;
        load16(ga, da);
        load16(pA1 + (long)t * 64, da + 4096);
        load16(gb, db);
        load16(pB1 + (long)t * 64, db + 4096);
    };

    bf16x8 a0[4], a1[4], b0[2], b1[2];
    const int NT = K >> 6, NI = NT >> 1;

    // prologue: stage t0->buf0, t1->buf1; wait buf0 (4 newest outstanding ok)
    stg(0, 0);
    stg(1, 1);
    asm volatile("s_waitcnt vmcnt(4)" ::: "memory");
    SBAR; SCH;
    RDA(a0, A00); RDB(b0, B00);
    SCH;

    for (int i = 0; i < NI; ++i) {
        int t2 = 2 * i + 2; if (t2 >= NT) t2 -= 2;  // tail: restage, unused
        int t3 = 2 * i + 3; if (t3 >= NT) t3 -= 2;
        // phi1: MFMA buf0.ks0; pf buf0.ks1
        RDA(a1, A01); RDB(b1, B01);
        PRIO1; CL8(a0, b0); PRIO0;
        PH6;
        VMC0;   // certify buf1 staged (only those 4 loads outstanding)
        SBAR; SCH;
        // phi2: stage buf0 <- t+2; pf buf1.ks0; MFMA buf0.ks1
        stg(0, t2);
        RDA(a0, A10); RDB(b0, B10);
        PRIO1; CL8(a1, b1); PRIO0;
        PH6;
        // phi3: pf buf1.ks1; MFMA buf1.ks0
        RDA(a1, A11); RDB(b1, B11);
        PRIO1; CL8(a0, b0); PRIO0;
        PH6;
        VMC0;   // certify buf0(t+2) staged
        SBAR; SCH;
        // phi4: stage buf1 <- t+3; pf buf0(t+2).ks0; MFMA buf1.ks1
        stg(1, t3);
        RDA(a0, A00); RDB(b0, B00);
        PRIO1; CL8(a1, b1); PRIO0;
        PH6;
    }
    // drain garbage tail staging before LDS reuse (epilogue)
    VMC0;
    SBAR; SCH;
}

// Standard GEMM: C[M,N] = scale*A@B^T + bias, opt ReLU, bf16 out.
// CLAMPK: K clamped to (by+1)*128 - koff (causal PV); zero tile if <=0.
// dsc.trans: write transposed into vtb layout [batch][N][2048].
template <bool RELU, bool CLAMPK>
__global__ __launch_bounds__(512, 4) void mm8_std(
    MMArgs args, int M, int N, int K, int lda, int ldb, float scale, int GX)
{
    __shared__ __align__(16) bf16_t lds[32768];  // 64 KiB -> 2 blocks/CU
    const MMDesc dsc = args.g[blockIdx.z];

    const int lin = xcd_swz(blockIdx.x, gridDim.x);
    const int panel = lin / (8 * GX);
    const int rem = lin - panel * 8 * GX;
    const int bx = rem >> 3;
    const int by = panel * 8 + (rem & 7);
    const int m0 = by * 128, n0 = bx * 128;
    const int tid = threadIdx.x, w = tid >> 6, l = tid & 63;

    f32x4 acc[4][2];
    const f32x4 z4 = {0.f, 0.f, 0.f, 0.f};
#pragma unroll
    for (int i = 0; i < 4; ++i)
#pragma unroll
        for (int j = 0; j < 2; ++j) acc[i][j] = z4;

    int Keff = K;
    if (CLAMPK) {
        int km = (by + 1) * 128 - dsc.koff;
        Keff = km < K ? km : K;
    }
    if (!CLAMPK || Keff > 0)
        mm8_core(dsc.A + (long)m0 * lda, dsc.B + (long)n0 * ldb,
                 lda, ldb, Keff, lds, w, l, acc);

    // epilogue: bias/scale/relu -> LDS (stride 136) -> coalesced uint4 out
    const int fr = l & 15, erow = (l >> 4) * 4;
    const int wm = (w >> 2) * 64, wn = (w & 3) * 32;
    bf16_t* ctb = lds;
    __hip_bfloat16* ct = (__hip_bfloat16*)lds;
#pragma unroll
    for (int nj = 0; nj < 2; ++nj) {
        const int cl = wn + nj * 16 + fr;
        const float bv = dsc.bias ? dsc.bias[n0 + cl] : 0.f;
#pragma unroll
        for (int mi = 0; mi < 4; ++mi) {
            const int lr = wm + mi * 16 + erow;
            const f32x4 a = acc[mi][nj];
            if (dsc.trans) {
                bf16x4 p;
#pragma unroll
                for (int r = 0; r < 4; ++r) {
                    float v = a[r] * scale + bv;
                    if (RELU) v = fmaxf(v, 0.f);
                    p[r] = (bf16_t)v;
                }
                *(bf16x4*)(ctb + cl * 136 + lr) = p;
            } else {
#pragma unroll
                for (int r = 0; r < 4; ++r) {
                    float v = a[r] * scale + bv;
                    if (RELU) v = fmaxf(v, 0.f);
                    ct[(lr + r) * 136 + cl] = __float2bfloat16(v);
                }
            }
        }
    }
    __syncthreads();
    if (dsc.trans) {  // V projection -> vtb[batch][e][s]; ct is [col][row]
        __hip_bfloat16* base = dsc.C + ((long)(m0 >> 11) * N + n0) * 2048
                             + (m0 & 2047);
#pragma unroll
        for (int u = 0; u < 4; ++u) {
            const int e = u * 4096 + tid * 8;
            const int ec = e >> 7, s = e & 127;
            *(uint4*)(base + (long)ec * 2048 + s)
                = *(const uint4*)(ct + ec * 136 + s);
        }
    } else {
        __hip_bfloat16* base = dsc.C + (long)m0 * N + n0;
#pragma unroll
        for (int u = 0; u < 4; ++u) {
            const int e = u * 4096 + tid * 8;
            const int rl = e >> 7, cl = e & 127;
            *(uint4*)(base + (long)rl * N + cl)
                = *(const uint4*)(ct + rl * 136 + cl);
        }
    }
}

// QK^T with fused exp epilogue: P~ = exp(scale*(A@B^T)) bf16, row sums -> lsum.
template <bool CAUSAL>
__global__ __launch_bounds__(512, 4) void mm8_exp(
    MMArgs args, int N, int K, int lda, int ldb, float scale, int GX)
{
    __shared__ __align__(16) bf16_t lds[32768];
    const MMDesc dsc = args.g[blockIdx.z];

    int bx, by;
    if (CAUSAL) {
        const int t = xcd_swz(blockIdx.x, gridDim.x);
        by = (int)((sqrtf(8.f * t + 1.f) - 1.f) * 0.5f);
        while ((by + 1) * (by + 2) / 2 <= t) ++by;
        while (by * (by + 1) / 2 > t) --by;
        bx = t - by * (by + 1) / 2;
    } else {
        const int lin = xcd_swz(blockIdx.x, gridDim.x);
        const int panel = lin / (8 * GX);
        const int rem = lin - panel * 8 * GX;
        bx = rem >> 3;
        by = panel * 8 + (rem & 7);
    }
    const int m0 = by * 128, n0 = bx * 128;
    const int tid = threadIdx.x, w = tid >> 6, l = tid & 63;

    f32x4 acc[4][2];
    const f32x4 z4 = {0.f, 0.f, 0.f, 0.f};
#pragma unroll
    for (int i = 0; i < 4; ++i)
#pragma unroll
        for (int j = 0; j < 2; ++j) acc[i][j] = z4;

    mm8_core(dsc.A + (long)m0 * lda, dsc.B + (long)n0 * ldb,
             lda, ldb, K, lds, w, l, acc);

    const int fr = l & 15, erow = (l >> 4) * 4;
    const int wm = (w >> 2) * 64, wn = (w & 3) * 32;
    __hip_bfloat16* ct = (__hip_bfloat16*)lds;
#pragma unroll
    for (int mi = 0; mi < 4; ++mi) {
        const int lr = wm + mi * 16 + erow;
#pragma unroll
        for (int r = 0; r < 4; ++r) {
            const int grow = m0 + lr + r;
            float rs = 0.f;
#pragma unroll
            for (int nj = 0; nj < 2; ++nj) {
                const int cl = wn + nj * 16 + fr;
                float e;
                if (CAUSAL && (n0 + cl) > grow)
                    e = 0.f;
                else
                    e = __expf(acc[mi][nj][r] * scale);
                ct[(lr + r) * 136 + cl] = __float2bfloat16(e);
                rs += e;
            }
#pragma unroll
            for (int o = 8; o > 0; o >>= 1) rs += __shfl_down(rs, o, 16);
            if ((l & 15) == 0) atomicAdd(&dsc.lsum[grow], rs);
        }
    }
    __syncthreads();
    __hip_bfloat16* base = dsc.C + (long)m0 * N + n0;
#pragma unroll
    for (int u = 0; u < 4; ++u) {
        const int e = u * 4096 + tid * 8;
        const int rl = e >> 7, cl = e & 127;
        *(uint4*)(base + (long)rl * N + cl)
            = *(const uint4*)(ct + rl * 136 + cl);
    }
}

// ---------------- reductions ----------------
__device__ __forceinline__ float waveReduceSum(float v) {
#pragma unroll
    for (int o = 32; o > 0; o >>= 1) v += __shfl_down(v, o, 64);
    return v;
}
__device__ __forceinline__ float blockReduceSum(float v, float* s) {
    int lane = threadIdx.x & 63, w = threadIdx.x >> 6;
    v = waveReduceSum(v);
    __syncthreads();
    if (lane == 0) s[w] = v;
    __syncthreads();
    return s[0] + s[1] + s[2] + s[3];
}

// out = LayerNorm(xbase + t) * g + beta.  h1,h2 bf16 partials.
template <bool BR, bool XF32>
__global__ __launch_bounds__(256) void ln_kernel(
    const float* __restrict__ xf, const __hip_bfloat16* __restrict__ xh,
    const __hip_bfloat16* __restrict__ h1, const __hip_bfloat16* __restrict__ h2,
    const float* __restrict__ hbias, const float* __restrict__ lsum,
    const float* __restrict__ g, const float* __restrict__ beta,
    float* __restrict__ outf, __hip_bfloat16* __restrict__ outb) {
    __shared__ float red[4];
    const int E = 768;
    const long row = blockIdx.x;
    const float hscale = lsum ? (1.f / lsum[row]) : 1.f;

    float vals[3];
    float sum = 0.f;
#pragma unroll
    for (int i = 0; i < 3; ++i) {
        int c = threadIdx.x + i * 256;
        float t = __bfloat162float(h1[row * E + c]) + __bfloat162float(h2[row * E + c]);
        if (BR) t = fmaxf(t + hbias[c], 0.f);
        else t *= hscale;
        float xv = XF32 ? xf[row * E + c] : __bfloat162float(xh[row * E + c]);
        vals[i] = xv + t;
        sum += vals[i];
    }
    sum = blockReduceSum(sum, red);
    const float mean = sum * (1.f / 768.f);

    float ss = 0.f;
#pragma unroll
    for (int i = 0; i < 3; ++i) {
        float d = vals[i] - mean;
        ss += d * d;
    }
    ss = blockReduceSum(ss, red);
    const float inv = rsqrtf(ss * (1.f / 768.f) + 1e-5f);

#pragma unroll
    for (int i = 0; i < 3; ++i) {
        int c = threadIdx.x + i * 256;
        float v = (vals[i] - mean) * inv * g[c] + beta[c];
        if (outf) outf[row * E + c] = v;
        if (outb) outb[row * E + c] = __float2bfloat16(v);
    }
}

// one launch converts all fp32->bf16 (8 weights + x + kv) and zeroes lsum.
struct CvtPtrs {
    const float* s[10];
    __hip_bfloat16* d[10];
    float* zero;  // 2*Nr floats to zero
};
__global__ __launch_bounds__(256) void cvt_all(CvtPtrs p) {
    int bid = blockIdx.x, seg, off;
    if (bid >= 20352) {  // zero lsum1+lsum2: 16 blocks x 256 x 4 floats
        int i = (bid - 20352) * 1024 + threadIdx.x * 4;
        float4 z = {0.f, 0.f, 0.f, 0.f};
        *(float4*)(p.zero + i) = z;
        return;
    }
    if (bid < 3456) {
        seg = bid / 576;
        off = (bid % 576) * 1024;
    } else if (bid < 8064) {
        int t = bid - 3456;
        seg = 6 + t / 2304;
        off = (t % 2304) * 1024;
    } else {
        int t = bid - 8064;
        seg = 8 + t / 6144;
        off = (t % 6144) * 1024;
    }
    const float* s = p.s[seg];
    __hip_bfloat16* d = p.d[seg];
    int i = off + threadIdx.x * 4;
    float4 v = *(const float4*)(s + i);
    d[i + 0] = __float2bfloat16(v.x);
    d[i + 1] = __float2bfloat16(v.y);
    d[i + 2] = __float2bfloat16(v.z);
    d[i + 3] = __float2bfloat16(v.w);
}

extern "C" void kernel_launch(void* const* d_in, const int* in_sizes, int n_in,
                              void* d_out, int out_size, void* d_ws, size_t ws_size,
                              hipStream_t stream) {
    const int Bb = 4, S = 2048, E = 768, DFF = 3072;
    const int Nr = Bb * S;  // 8192

    const float* x    = (const float*)d_in[0];
    const float* kv   = (const float*)d_in[1];
    const float* wq_w = (const float*)d_in[2];
    const float* wq_b = (const float*)d_in[3];
    const float* wk_w = (const float*)d_in[4];
    const float* wk_b = (const float*)d_in[5];
    const float* wv_w = (const float*)d_in[6];
    const float* wv_b = (const float*)d_in[7];
    const float* ln1g = (const float*)d_in[8];
    const float* ln1b = (const float*)d_in[9];
    const float* wq2w = (const float*)d_in[10];
    const float* wq2b = (const float*)d_in[11];
    const float* wk2w = (const float*)d_in[12];
    const float* wk2b = (const float*)d_in[13];
    const float* wv2w = (const float*)d_in[14];
    const float* wv2b = (const float*)d_in[15];
    const float* ln2g = (const float*)d_in[16];
    const float* ln2b = (const float*)d_in[17];
    const float* w1   = (const float*)d_in[18];
    const float* b1   = (const float*)d_in[19];
    const float* w2   = (const float*)d_in[20];
    const float* b2   = (const float*)d_in[21];
    const float* ln3g = (const float*)d_in[22];
    const float* ln3b = (const float*)d_in[23];
    float* out = (float*)d_out;

    // ---- workspace (bump allocator, 256B aligned) ~155 MB ----
    char* wsp = (char*)d_ws;
    auto alloc = [&](size_t bytes) {
        char* p = wsp;
        wsp += (bytes + 255) & ~(size_t)255;
        return p;
    };
    const size_t nSE = (size_t)Nr * E;       // 6,291,456
    const size_t nSS = (size_t)Bb * S * S;   // 16,777,216
    __hip_bfloat16* Pb   = (__hip_bfloat16*)alloc(nSS * 2);   // 33.5 MB
    __hip_bfloat16* qb   = (__hip_bfloat16*)alloc(nSE * 2);
    __hip_bfloat16* kb   = (__hip_bfloat16*)alloc(nSE * 2);
    __hip_bfloat16* hffb = Pb;  // MLP hidden overlays Pb+qb+kb (58.7 >= 50.3 MB)
    __hip_bfloat16* vtb  = (__hip_bfloat16*)alloc(nSE * 2);   // V^T [b][E][S]
    __hip_bfloat16* xb   = (__hip_bfloat16*)alloc(nSE * 2);
    __hip_bfloat16* kvb  = (__hip_bfloat16*)alloc(nSE * 2);
    __hip_bfloat16* actb = (__hip_bfloat16*)alloc(nSE * 2);   // residual chain
    __hip_bfloat16* hA   = (__hip_bfloat16*)alloc(nSE * 2);   // split-K partial A
    __hip_bfloat16* hB   = (__hip_bfloat16*)alloc(nSE * 2);   // split-K partial B
    __hip_bfloat16* wqb   = (__hip_bfloat16*)alloc((size_t)E * E * 2);
    __hip_bfloat16* wkb   = (__hip_bfloat16*)alloc((size_t)E * E * 2);
    __hip_bfloat16* wvb   = (__hip_bfloat16*)alloc((size_t)E * E * 2);
    __hip_bfloat16* wq2bm = (__hip_bfloat16*)alloc((size_t)E * E * 2);
    __hip_bfloat16* wk2bm = (__hip_bfloat16*)alloc((size_t)E * E * 2);
    __hip_bfloat16* wv2bm = (__hip_bfloat16*)alloc((size_t)E * E * 2);
    __hip_bfloat16* w1b   = (__hip_bfloat16*)alloc((size_t)DFF * E * 2);
    __hip_bfloat16* w2b   = (__hip_bfloat16*)alloc((size_t)E * DFF * 2);
    float* lsum1 = (float*)alloc((size_t)Nr * 4);
    float* lsum2 = (float*)alloc((size_t)Nr * 4);

    // K2 / V2^T live in d_out used as scratch (exactly 2*nSE*2 bytes = out_size);
    // both are dead before ln3 writes the real output.
    __hip_bfloat16* k2b  = (__hip_bfloat16*)d_out;
    __hip_bfloat16* vtb2 = k2b + nSE;

    const float scale = 1.0f / sqrtf((float)E);
    const dim3 blk(256);
    const dim3 blk5(512);

    // ---- all conversions + lsum zeroing in one launch ----
    CvtPtrs cp;
    cp.s[0] = wq_w; cp.d[0] = wqb;
    cp.s[1] = wk_w; cp.d[1] = wkb;
    cp.s[2] = wv_w; cp.d[2] = wvb;
    cp.s[3] = wq2w; cp.d[3] = wq2bm;
    cp.s[4] = wk2w; cp.d[4] = wk2bm;
    cp.s[5] = wv2w; cp.d[5] = wv2bm;
    cp.s[6] = w1;   cp.d[6] = w1b;
    cp.s[7] = w2;   cp.d[7] = w2b;
    cp.s[8] = x;    cp.d[8] = xb;
    cp.s[9] = kv;   cp.d[9] = kvb;
    cp.zero = lsum1;  // lsum1+lsum2 contiguous (2*Nr floats)
    cvt_all<<<8064 + 12288 + 16, blk, 0, stream>>>(cp);

    // ---- fused projections: Q,K,V(self from xb) + K2,V2(cross from kvb) ----
    {   // 5 z-slices x 384 blocks = 1920 blocks (~3.75 rounds at 2/CU)
        MMArgs a{};
        a.g[0] = {(const bf16_t*)xb,  (const bf16_t*)wqb,   wq_b, qb,   nullptr, 0, 0};
        a.g[1] = {(const bf16_t*)xb,  (const bf16_t*)wkb,   wk_b, kb,   nullptr, 0, 0};
        a.g[2] = {(const bf16_t*)xb,  (const bf16_t*)wvb,   wv_b, vtb,  nullptr, 0, 1};
        a.g[3] = {(const bf16_t*)kvb, (const bf16_t*)wk2bm, wk2b, k2b,  nullptr, 0, 0};
        a.g[4] = {(const bf16_t*)kvb, (const bf16_t*)wv2bm, wv2b, vtb2, nullptr, 0, 1};
        mm8_std<false, false><<<dim3(384, 1, 5), blk5, 0, stream>>>(
            a, Nr, E, E, E, E, 1.f, 6);
    }
    // ---- causal self-attention ----
    {   // causal QK^T + exp: 136 triangle tiles x 4 batches
        MMArgs a{};
        for (int b = 0; b < 4; ++b)
            a.g[b] = {(const bf16_t*)qb + (long)b * S * E,
                      (const bf16_t*)kb + (long)b * S * E, nullptr,
                      Pb + (long)b * S * S, lsum1 + b * S, 0, 0};
        mm8_exp<true><<<dim3(136, 1, 4), blk5, 0, stream>>>(a, S, E, E, E, scale, 16);
    }
    {   // causal PV split-K=2 with K-clamp, bf16 partials
        MMArgs a{};
        for (int b = 0; b < 4; ++b)
            for (int ks = 0; ks < 2; ++ks)
                a.g[b * 2 + ks] = {(const bf16_t*)Pb + (long)b * S * S + ks * 1024,
                                   (const bf16_t*)vtb + (long)b * E * S + ks * 1024,
                                   nullptr, (ks ? hB : hA) + (long)b * S * E,
                                   nullptr, ks * 1024, 0};
        mm8_std<false, true><<<dim3(96, 1, 8), blk5, 0, stream>>>(
            a, S, E, 1024, S, S, 1.f, 6);
    }
    ln_kernel<false, false><<<Nr, blk, 0, stream>>>(
        nullptr, xb, hA, hB, nullptr, lsum1, ln1g, ln1b, nullptr, actb);

    // ---- cross-attention ----
    {   // Q2 projection only (K2/V2 already done): 384 blocks
        MMArgs a{};
        a.g[0] = {(const bf16_t*)actb, (const bf16_t*)wq2bm, wq2b, qb, nullptr, 0, 0};
        mm8_std<false, false><<<dim3(384, 1, 1), blk5, 0, stream>>>(
            a, Nr, E, E, E, E, 1.f, 6);
    }
    {   // full QK^T + exp: 256 tiles x 4 batches
        MMArgs a{};
        for (int b = 0; b < 4; ++b)
            a.g[b] = {(const bf16_t*)qb + (long)b * S * E,
                      (const bf16_t*)k2b + (long)b * S * E, nullptr,
                      Pb + (long)b * S * S, lsum2 + b * S, 0, 0};
        mm8_exp<false><<<dim3(256, 1, 4), blk5, 0, stream>>>(a, S, E, E, E, scale, 16);
    }
    {   // full PV split-K=2, bf16 partials
        MMArgs a{};
        for (int b = 0; b < 4; ++b)
            for (int ks = 0; ks < 2; ++ks)
                a.g[b * 2 + ks] = {(const bf16_t*)Pb + (long)b * S * S + ks * 1024,
                                   (const bf16_t*)vtb2 + (long)b * E * S + ks * 1024,
                                   nullptr, (ks ? hB : hA) + (long)b * S * E,
                                   nullptr, 0, 0};
        mm8_std<false, false><<<dim3(96, 1, 8), blk5, 0, stream>>>(
            a, S, E, 1024, S, S, 1.f, 6);
    }
    ln_kernel<false, false><<<Nr, blk, 0, stream>>>(
        nullptr, actb, hA, hB, nullptr, lsum2, ln2g, ln2b, nullptr, actb);

    // ---- MLP ----
    {   // MLP1: fused bias+ReLU (hffb overlays Pb/qb/kb): 1536 blocks
        MMArgs a{};
        a.g[0] = {(const bf16_t*)actb, (const bf16_t*)w1b, b1, hffb, nullptr, 0, 0};
        mm8_std<true, false><<<dim3(1536, 1, 1), blk5, 0, stream>>>(
            a, Nr, DFF, E, E, E, 1.f, 24);
    }
    {   // MLP2 split-K=2, bf16 partials; bias+ReLU applied in ln3
        MMArgs a{};
        a.g[0] = {(const bf16_t*)hffb, (const bf16_t*)w2b, nullptr, hA, nullptr, 0, 0};
        a.g[1] = {(const bf16_t*)hffb + 1536, (const bf16_t*)w2b + 1536, nullptr,
                  hB, nullptr, 0, 0};
        mm8_std<false, false><<<dim3(384, 1, 2), blk5, 0, stream>>>(
            a, Nr, E, 1536, DFF, DFF, 1.f, 6);
    }
    ln_kernel<true, false><<<Nr, blk, 0, stream>>>(
        nullptr, actb, hA, hB, b2, nullptr, ln3g, ln3b, out, nullptr);
}

// Round 7
// 457.618 us; speedup vs baseline: 1.1384x; 1.1384x over previous
//
#include <hip/hip_runtime.h>
#include <hip/hip_bf16.h>
#include <math.h>

// ---------------------------------------------------------------------------
// TransformerDecoderBlock  (B=4, S=2048, E=768, DFF=3072)
// Round 13: mixed-tile. R5's 256x256 pipelined core (best per-FLOP: proj,
// QK^T x2, cross-PV, MLP2) + R6's 128x128 2-blocks/CU core for the three
// fill-starved dispatches: Q2 (96->384 blocks), causal PV (192->768, finer
// K-clamp), MLP1 (384 ragged -> 1536 = 3.0 perfect rounds).
// Both cores: pipelined phases (prefetch next phase's frags ∥ MFMA cluster),
// T2 swizzle staging via global_load_lds, counted vmcnt, setprio, SGB pins.
// ---------------------------------------------------------------------------

typedef __bf16 bf16_t;
typedef bf16_t bf16x4 __attribute__((ext_vector_type(4)));
typedef bf16_t bf16x8 __attribute__((ext_vector_type(8)));
typedef float f32x4 __attribute__((ext_vector_type(4)));

struct MMDesc {
    const bf16_t* A;
    const bf16_t* B;
    const float* bias;
    __hip_bfloat16* C;
    float* lsum;
    int koff;
    int trans;  // epilogue writes C transposed into [E][2048-per-batch] layout
};
struct MMArgs { MMDesc g[8]; };

// bijective XCD swizzle (m204): contiguous chunk per XCD, any grid size
__device__ __forceinline__ int xcd_swz(int bid, int nwg) {
    const int q = nwg >> 3, r = nwg & 7;
    const int xcd = bid & 7, o = bid >> 3;
    const int base = (xcd < r) ? xcd * (q + 1) : r * (q + 1) + (xcd - r) * q;
    return base + o;
}

// async global->LDS, 16B per lane. LDS dest = wave-uniform base + lane*16.
__device__ __forceinline__ void load16(const bf16_t* g, bf16_t* l) {
    __builtin_amdgcn_global_load_lds(
        (const __attribute__((address_space(1))) unsigned int*)g,
        (__attribute__((address_space(3))) unsigned int*)l, 16, 0, 0);
}

#define SBAR asm volatile("s_barrier" ::: "memory")
#define SCH  __builtin_amdgcn_sched_barrier(0)
#define PRIO1 __builtin_amdgcn_s_setprio(1)
#define PRIO0 __builtin_amdgcn_s_setprio(0)
#define VMC0 asm volatile("s_waitcnt vmcnt(0)" ::: "memory")

// ---- 256^2 core helpers (R5) ----
#define RDA4(dst, base, H) do { \
    _Pragma("unroll") \
    for (int i_ = 0; i_ < 4; ++i_) \
        dst[i_] = *(const bf16x8*)((base) + (H) + i_ * 1024); \
} while (0)
#define RDB4(dst, base) do { \
    dst[0] = *(const bf16x8*)(base); \
    dst[1] = *(const bf16x8*)((base) + 1024); \
    dst[2] = *(const bf16x8*)((base) + 8192); \
    dst[3] = *(const bf16x8*)((base) + 8192 + 1024); \
} while (0)
#define CL16(mh, A_, B_) do { \
    _Pragma("unroll") \
    for (int mi = 0; mi < 4; ++mi) \
    _Pragma("unroll") \
    for (int nj = 0; nj < 4; ++nj) \
        acc[(mh) * 4 + mi][nj] = __builtin_amdgcn_mfma_f32_16x16x32_bf16( \
            A_[mi], B_[nj], acc[(mh) * 4 + mi][nj], 0, 0, 0); \
} while (0)
#define PH(nr) do { \
    __builtin_amdgcn_sched_group_barrier(0x100, nr, 0); \
    __builtin_amdgcn_sched_group_barrier(0x008, 16, 0); \
    SCH; \
} while (0)

// 256x256 tile, BK=64, 8 waves. LDS elems: [buf:32768][op:16384][half:8192]
// [row:64], 16B slot swizzle slot ^= (row&7). K multiple of 128.
__device__ __forceinline__ void mm8_core(
    const bf16_t* Ag, const bf16_t* Bg, int lda, int ldb, int K,
    bf16_t* lds, int w, int l, f32x4 acc[8][4])
{
    const long ldal = lda, ldbl = ldb;
    const int fr = l & 15, kq = l >> 4;
    const int rr = w * 8 + (l >> 3);
    const int c8e = ((l & 7) ^ (l >> 3)) * 8;
    const bf16_t* pA[2];
    const bf16_t* pB[2];
    pA[0] = Ag + (long)rr * ldal + c8e;
    pA[1] = pA[0] + 128 * ldal;
    pB[0] = Bg + (long)rr * ldbl + c8e;
    pB[1] = pB[0] + 128 * ldbl;
    const int s0 = ((0 + kq) ^ (fr & 7)) * 8;
    const int s1 = ((4 + kq) ^ (fr & 7)) * 8;
    const int arow = ((w >> 2) * 64 + fr) * 64;
    const int brow = ((w & 3) * 32 + fr) * 64;
    const bf16_t* A00 = lds + arow + s0;
    const bf16_t* A01 = lds + arow + s1;
    const bf16_t* A10 = lds + 32768 + arow + s0;
    const bf16_t* A11 = lds + 32768 + arow + s1;
    const bf16_t* B00 = lds + 16384 + brow + s0;
    const bf16_t* B01 = lds + 16384 + brow + s1;
    const bf16_t* B10 = lds + 49152 + brow + s0;
    const bf16_t* B11 = lds + 49152 + brow + s1;
    bf16_t* stA = lds + w * 512;
    bf16_t* stB = lds + 16384 + w * 512;

    auto stg = [&](int b, int isB, int h, int t) {
        const bf16_t* g = (isB ? pB[h] : pA[h]) + (long)t * 64;
        bf16_t* d = (isB ? stB : stA) + b * 32768 + h * 8192;
        load16(g, d);
        load16(g + 64 * (isB ? ldbl : ldal), d + 4096);
    };

    bf16x8 a0[4], a1[4], b0[4], b1[4];
    const int NT = K >> 6, NI = NT >> 1;

    stg(0, 0, 0, 0); stg(0, 1, 0, 0); stg(0, 0, 1, 0); stg(0, 1, 1, 0);
    stg(1, 0, 0, 1); stg(1, 1, 0, 1);
    asm volatile("s_waitcnt vmcnt(4)" ::: "memory");
    SBAR; SCH;
    RDA4(a0, A00, 0); RDB4(b0, B00);
    SCH;

    for (int i = 0; i < NI; ++i) {
        const int tn1 = 2 * i + 1;
        int tn2 = 2 * i + 2; if (tn2 >= NT) tn2 -= 2;
        int tn3 = 2 * i + 3; if (tn3 >= NT) tn3 -= 2;
        // even tile (buf0)
        RDA4(a1, A01, 0); RDB4(b1, B01);
        stg(1, 0, 1, tn1); stg(1, 1, 1, tn1);
        PRIO1; CL16(0, a0, b0); PRIO0;
        PH(8);
        RDA4(a0, A00, 8192);
        PRIO1; CL16(0, a1, b1); PRIO0;
        PH(4);
        RDA4(a1, A01, 8192);
        PRIO1; CL16(1, a0, b0); PRIO0;
        PH(4);
        VMC0;
        SBAR; SCH;
        stg(0, 0, 0, tn2); stg(0, 1, 0, tn2);
        RDA4(a0, A10, 0); RDB4(b0, B10);
        PRIO1; CL16(1, a1, b1); PRIO0;
        PH(8);
        // odd tile (buf1)
        RDA4(a1, A11, 0); RDB4(b1, B11);
        stg(0, 0, 1, tn2); stg(0, 1, 1, tn2);
        PRIO1; CL16(0, a0, b0); PRIO0;
        PH(8);
        RDA4(a0, A10, 8192);
        PRIO1; CL16(0, a1, b1); PRIO0;
        PH(4);
        RDA4(a1, A11, 8192);
        PRIO1; CL16(1, a0, b0); PRIO0;
        PH(4);
        VMC0;
        SBAR; SCH;
        stg(1, 0, 0, tn3); stg(1, 1, 0, tn3);
        RDA4(a0, A00, 0); RDB4(b0, B00);
        PRIO1; CL16(1, a1, b1); PRIO0;
        PH(8);
    }
    VMC0;
    SBAR; SCH;
}

// ---- 128^2 core (R6): BK=64, 8 waves, 64 KiB LDS -> 2 blocks/CU ----
#define RDA2(dst, base) do { \
    _Pragma("unroll") \
    for (int i_ = 0; i_ < 4; ++i_) \
        dst[i_] = *(const bf16x8*)((base) + i_ * 1024); \
} while (0)
#define RDB2(dst, base) do { \
    dst[0] = *(const bf16x8*)(base); \
    dst[1] = *(const bf16x8*)((base) + 1024); \
} while (0)
#define CL8(A_, B_) do { \
    _Pragma("unroll") \
    for (int mi = 0; mi < 4; ++mi) \
    _Pragma("unroll") \
    for (int nj = 0; nj < 2; ++nj) \
        acc[mi][nj] = __builtin_amdgcn_mfma_f32_16x16x32_bf16( \
            A_[mi], B_[nj], acc[mi][nj], 0, 0, 0); \
} while (0)
#define PH6 do { \
    __builtin_amdgcn_sched_group_barrier(0x100, 6, 0); \
    __builtin_amdgcn_sched_group_barrier(0x008, 8, 0); \
    SCH; \
} while (0)

__device__ __forceinline__ void mm4_core(
    const bf16_t* Ag, const bf16_t* Bg, int lda, int ldb, int K,
    bf16_t* lds, int w, int l, f32x4 acc[4][2])
{
    const long ldal = lda, ldbl = ldb;
    const int fr = l & 15, kq = l >> 4;
    const int rr = w * 8 + (l >> 3);
    const int c8e = ((l & 7) ^ (l >> 3)) * 8;
    const bf16_t* pA0 = Ag + (long)rr * ldal + c8e;
    const bf16_t* pA1 = pA0 + 64 * ldal;
    const bf16_t* pB0 = Bg + (long)rr * ldbl + c8e;
    const bf16_t* pB1 = pB0 + 64 * ldbl;
    const int s0 = ((0 + kq) ^ (fr & 7)) * 8;
    const int s1 = ((4 + kq) ^ (fr & 7)) * 8;
    const int arow = ((w >> 2) * 64 + fr) * 64;
    const int brow = ((w & 3) * 32 + fr) * 64;
    const bf16_t* A00 = lds + arow + s0;
    const bf16_t* A01 = lds + arow + s1;
    const bf16_t* A10 = lds + 16384 + arow + s0;
    const bf16_t* A11 = lds + 16384 + arow + s1;
    const bf16_t* B00 = lds + 8192 + brow + s0;
    const bf16_t* B01 = lds + 8192 + brow + s1;
    const bf16_t* B10 = lds + 24576 + brow + s0;
    const bf16_t* B11 = lds + 24576 + brow + s1;
    bf16_t* stA = lds + w * 512;
    bf16_t* stB = lds + 8192 + w * 512;

    auto stg = [&](int b, int t) {
        const bf16_t* ga = pA0 + (long)t * 64;
        const bf16_t* gb = pB0 + (long)t * 64;
        bf16_t* da = stA + b * 16384;
        bf16_t* db = stB + b * 16384;
        load16(ga, da);
        load16(pA1 + (long)t * 64, da + 4096);
        load16(gb, db);
        load16(pB1 + (long)t * 64, db + 4096);
    };

    bf16x8 a0[4], a1[4], b0[2], b1[2];
    const int NT = K >> 6, NI = NT >> 1;

    stg(0, 0);
    stg(1, 1);
    asm volatile("s_waitcnt vmcnt(4)" ::: "memory");
    SBAR; SCH;
    RDA2(a0, A00); RDB2(b0, B00);
    SCH;

    for (int i = 0; i < NI; ++i) {
        int t2 = 2 * i + 2; if (t2 >= NT) t2 -= 2;
        int t3 = 2 * i + 3; if (t3 >= NT) t3 -= 2;
        RDA2(a1, A01); RDB2(b1, B01);
        PRIO1; CL8(a0, b0); PRIO0;
        PH6;
        VMC0;
        SBAR; SCH;
        stg(0, t2);
        RDA2(a0, A10); RDB2(b0, B10);
        PRIO1; CL8(a1, b1); PRIO0;
        PH6;
        RDA2(a1, A11); RDB2(b1, B11);
        PRIO1; CL8(a0, b0); PRIO0;
        PH6;
        VMC0;
        SBAR; SCH;
        stg(1, t3);
        RDA2(a0, A00); RDB2(b0, B00);
        PRIO1; CL8(a1, b1); PRIO0;
        PH6;
    }
    VMC0;
    SBAR; SCH;
}

// ---- 256^2 kernels ----
template <bool RELU, bool CLAMPK>
__global__ __launch_bounds__(512, 2) void mm8_std(
    MMArgs args, int M, int N, int K, int lda, int ldb, float scale, int GX)
{
    __shared__ __align__(16) bf16_t lds[65536];  // 128 KiB
    const MMDesc dsc = args.g[blockIdx.z];

    const int lin = xcd_swz(blockIdx.x, gridDim.x);
    const int panel = lin / (8 * GX);
    const int rem = lin - panel * 8 * GX;
    const int bx = rem >> 3;
    const int by = panel * 8 + (rem & 7);
    const int m0 = by * 256, n0 = bx * 256;
    const int tid = threadIdx.x, w = tid >> 6, l = tid & 63;

    f32x4 acc[8][4];
    const f32x4 z4 = {0.f, 0.f, 0.f, 0.f};
#pragma unroll
    for (int i = 0; i < 8; ++i)
#pragma unroll
        for (int j = 0; j < 4; ++j) acc[i][j] = z4;

    int Keff = K;
    if (CLAMPK) {
        int km = (by + 1) * 256 - dsc.koff;
        Keff = km < K ? km : K;
    }
    if (!CLAMPK || Keff > 0)
        mm8_core(dsc.A + (long)m0 * lda, dsc.B + (long)n0 * ldb,
                 lda, ldb, Keff, lds, w, l, acc);

    const int fr = l & 15, erow = (l >> 4) * 4;
    const int wrow = (w >> 2) * 64, wcol = (w & 3) * 32;
    bf16_t* ctb = lds;
    __hip_bfloat16* ct = (__hip_bfloat16*)lds;
#pragma unroll
    for (int mh = 0; mh < 2; ++mh) {
        if (mh) __syncthreads();
#pragma unroll
        for (int nh = 0; nh < 2; ++nh)
#pragma unroll
            for (int ni = 0; ni < 2; ++ni) {
                const int cl = nh * 128 + wcol + ni * 16 + fr;
                const float bv = dsc.bias ? dsc.bias[n0 + cl] : 0.f;
#pragma unroll
                for (int mi = 0; mi < 4; ++mi) {
                    const int lr = wrow + mi * 16 + erow;
                    const f32x4 a = acc[mh * 4 + mi][nh * 2 + ni];
                    if (dsc.trans) {
                        bf16x4 p;
#pragma unroll
                        for (int r = 0; r < 4; ++r) {
                            float v = a[r] * scale + bv;
                            if (RELU) v = fmaxf(v, 0.f);
                            p[r] = (bf16_t)v;
                        }
                        *(bf16x4*)(ctb + cl * 140 + lr) = p;
                    } else {
#pragma unroll
                        for (int r = 0; r < 4; ++r) {
                            float v = a[r] * scale + bv;
                            if (RELU) v = fmaxf(v, 0.f);
                            ct[(lr + r) * 264 + cl] = __float2bfloat16(v);
                        }
                    }
                }
            }
        __syncthreads();
        if (dsc.trans) {
            __hip_bfloat16* base = dsc.C + ((long)(m0 >> 11) * N + n0) * 2048
                                 + (m0 & 2047) + mh * 128;
#pragma unroll
            for (int u = 0; u < 8; ++u) {
                const int e = u * 4096 + tid * 8;
                const int rl = e >> 7, cl = e & 127;
                const bf16_t* src = ctb + rl * 140 + cl;
                const uint2 lo = *(const uint2*)(src);
                const uint2 hi = *(const uint2*)(src + 4);
                const uint4 v = {lo.x, lo.y, hi.x, hi.y};
                *(uint4*)(base + (long)rl * 2048 + cl) = v;
            }
        } else {
            __hip_bfloat16* base = dsc.C + (long)(m0 + mh * 128) * N + n0;
#pragma unroll
            for (int u = 0; u < 8; ++u) {
                const int e = u * 4096 + tid * 8;
                *(uint4*)(base + (long)(e >> 8) * N + (e & 255))
                    = *(const uint4*)(ct + (e >> 8) * 264 + (e & 255));
            }
        }
    }
}

template <bool CAUSAL>
__global__ __launch_bounds__(512, 2) void mm8_exp(
    MMArgs args, int N, int K, int lda, int ldb, float scale, int GX)
{
    __shared__ __align__(16) bf16_t lds[65536];
    const MMDesc dsc = args.g[blockIdx.z];

    int bx, by;
    if (CAUSAL) {
        const int t = xcd_swz(blockIdx.x, gridDim.x);
        by = (int)((sqrtf(8.f * t + 1.f) - 1.f) * 0.5f);
        while ((by + 1) * (by + 2) / 2 <= t) ++by;
        while (by * (by + 1) / 2 > t) --by;
        bx = t - by * (by + 1) / 2;
    } else {
        const int lin = xcd_swz(blockIdx.x, gridDim.x);
        const int panel = lin / (8 * GX);
        const int rem = lin - panel * 8 * GX;
        bx = rem >> 3;
        by = panel * 8 + (rem & 7);
    }
    const int m0 = by * 256, n0 = bx * 256;
    const int tid = threadIdx.x, w = tid >> 6, l = tid & 63;

    f32x4 acc[8][4];
    const f32x4 z4 = {0.f, 0.f, 0.f, 0.f};
#pragma unroll
    for (int i = 0; i < 8; ++i)
#pragma unroll
        for (int j = 0; j < 4; ++j) acc[i][j] = z4;

    mm8_core(dsc.A + (long)m0 * lda, dsc.B + (long)n0 * ldb,
             lda, ldb, K, lds, w, l, acc);

    const int fr = l & 15, erow = (l >> 4) * 4;
    const int wrow = (w >> 2) * 64, wcol = (w & 3) * 32;
    __hip_bfloat16* ct = (__hip_bfloat16*)lds;
#pragma unroll
    for (int mh = 0; mh < 2; ++mh) {
        if (mh) __syncthreads();
#pragma unroll
        for (int mi = 0; mi < 4; ++mi) {
            const int lr = wrow + mi * 16 + erow;
#pragma unroll
            for (int r = 0; r < 4; ++r) {
                const int grow = m0 + mh * 128 + lr + r;
                float rs = 0.f;
#pragma unroll
                for (int nh = 0; nh < 2; ++nh)
#pragma unroll
                    for (int ni = 0; ni < 2; ++ni) {
                        const int cl = nh * 128 + wcol + ni * 16 + fr;
                        float e;
                        if (CAUSAL && (n0 + cl) > grow)
                            e = 0.f;
                        else
                            e = __expf(acc[mh * 4 + mi][nh * 2 + ni][r] * scale);
                        ct[(lr + r) * 264 + cl] = __float2bfloat16(e);
                        rs += e;
                    }
#pragma unroll
                for (int o = 8; o > 0; o >>= 1) rs += __shfl_down(rs, o, 16);
                if ((l & 15) == 0) atomicAdd(&dsc.lsum[grow], rs);
            }
        }
        __syncthreads();
        __hip_bfloat16* base = dsc.C + (long)(m0 + mh * 128) * N + n0;
#pragma unroll
        for (int u = 0; u < 8; ++u) {
            const int e = u * 4096 + tid * 8;
            *(uint4*)(base + (long)(e >> 8) * N + (e & 255))
                = *(const uint4*)(ct + (e >> 8) * 264 + (e & 255));
        }
    }
}

// ---- 128^2 kernel (fill-starved dispatches) ----
template <bool RELU, bool CLAMPK>
__global__ __launch_bounds__(512, 4) void mm4_std(
    MMArgs args, int M, int N, int K, int lda, int ldb, float scale, int GX)
{
    __shared__ __align__(16) bf16_t lds[32768];  // 64 KiB -> 2 blocks/CU
    const MMDesc dsc = args.g[blockIdx.z];

    const int lin = xcd_swz(blockIdx.x, gridDim.x);
    const int panel = lin / (8 * GX);
    const int rem = lin - panel * 8 * GX;
    const int bx = rem >> 3;
    const int by = panel * 8 + (rem & 7);
    const int m0 = by * 128, n0 = bx * 128;
    const int tid = threadIdx.x, w = tid >> 6, l = tid & 63;

    f32x4 acc[4][2];
    const f32x4 z4 = {0.f, 0.f, 0.f, 0.f};
#pragma unroll
    for (int i = 0; i < 4; ++i)
#pragma unroll
        for (int j = 0; j < 2; ++j) acc[i][j] = z4;

    int Keff = K;
    if (CLAMPK) {
        int km = (by + 1) * 128 - dsc.koff;
        Keff = km < K ? km : K;
    }
    if (!CLAMPK || Keff > 0)
        mm4_core(dsc.A + (long)m0 * lda, dsc.B + (long)n0 * ldb,
                 lda, ldb, Keff, lds, w, l, acc);

    const int fr = l & 15, erow = (l >> 4) * 4;
    const int wm = (w >> 2) * 64, wn = (w & 3) * 32;
    __hip_bfloat16* ct = (__hip_bfloat16*)lds;
#pragma unroll
    for (int nj = 0; nj < 2; ++nj) {
        const int cl = wn + nj * 16 + fr;
        const float bv = dsc.bias ? dsc.bias[n0 + cl] : 0.f;
#pragma unroll
        for (int mi = 0; mi < 4; ++mi) {
            const int lr = wm + mi * 16 + erow;
            const f32x4 a = acc[mi][nj];
#pragma unroll
            for (int r = 0; r < 4; ++r) {
                float v = a[r] * scale + bv;
                if (RELU) v = fmaxf(v, 0.f);
                ct[(lr + r) * 136 + cl] = __float2bfloat16(v);
            }
        }
    }
    __syncthreads();
    __hip_bfloat16* base = dsc.C + (long)m0 * N + n0;
#pragma unroll
    for (int u = 0; u < 4; ++u) {
        const int e = u * 4096 + tid * 8;
        const int rl = e >> 7, cl = e & 127;
        *(uint4*)(base + (long)rl * N + cl)
            = *(const uint4*)(ct + rl * 136 + cl);
    }
}

// ---------------- reductions ----------------
__device__ __forceinline__ float waveReduceSum(float v) {
#pragma unroll
    for (int o = 32; o > 0; o >>= 1) v += __shfl_down(v, o, 64);
    return v;
}
__device__ __forceinline__ float blockReduceSum(float v, float* s) {
    int lane = threadIdx.x & 63, w = threadIdx.x >> 6;
    v = waveReduceSum(v);
    __syncthreads();
    if (lane == 0) s[w] = v;
    __syncthreads();
    return s[0] + s[1] + s[2] + s[3];
}

// out = LayerNorm(xbase + t) * g + beta.  h1,h2 bf16 partials.
template <bool BR, bool XF32>
__global__ __launch_bounds__(256) void ln_kernel(
    const float* __restrict__ xf, const __hip_bfloat16* __restrict__ xh,
    const __hip_bfloat16* __restrict__ h1, const __hip_bfloat16* __restrict__ h2,
    const float* __restrict__ hbias, const float* __restrict__ lsum,
    const float* __restrict__ g, const float* __restrict__ beta,
    float* __restrict__ outf, __hip_bfloat16* __restrict__ outb) {
    __shared__ float red[4];
    const int E = 768;
    const long row = blockIdx.x;
    const float hscale = lsum ? (1.f / lsum[row]) : 1.f;

    float vals[3];
    float sum = 0.f;
#pragma unroll
    for (int i = 0; i < 3; ++i) {
        int c = threadIdx.x + i * 256;
        float t = __bfloat162float(h1[row * E + c]) + __bfloat162float(h2[row * E + c]);
        if (BR) t = fmaxf(t + hbias[c], 0.f);
        else t *= hscale;
        float xv = XF32 ? xf[row * E + c] : __bfloat162float(xh[row * E + c]);
        vals[i] = xv + t;
        sum += vals[i];
    }
    sum = blockReduceSum(sum, red);
    const float mean = sum * (1.f / 768.f);

    float ss = 0.f;
#pragma unroll
    for (int i = 0; i < 3; ++i) {
        float d = vals[i] - mean;
        ss += d * d;
    }
    ss = blockReduceSum(ss, red);
    const float inv = rsqrtf(ss * (1.f / 768.f) + 1e-5f);

#pragma unroll
    for (int i = 0; i < 3; ++i) {
        int c = threadIdx.x + i * 256;
        float v = (vals[i] - mean) * inv * g[c] + beta[c];
        if (outf) outf[row * E + c] = v;
        if (outb) outb[row * E + c] = __float2bfloat16(v);
    }
}

// one launch converts all fp32->bf16 (8 weights + x + kv) and zeroes lsum.
struct CvtPtrs {
    const float* s[10];
    __hip_bfloat16* d[10];
    float* zero;  // 2*Nr floats to zero
};
__global__ __launch_bounds__(256) void cvt_all(CvtPtrs p) {
    int bid = blockIdx.x, seg, off;
    if (bid >= 20352) {  // zero lsum1+lsum2: 16 blocks x 256 x 4 floats
        int i = (bid - 20352) * 1024 + threadIdx.x * 4;
        float4 z = {0.f, 0.f, 0.f, 0.f};
        *(float4*)(p.zero + i) = z;
        return;
    }
    if (bid < 3456) {
        seg = bid / 576;
        off = (bid % 576) * 1024;
    } else if (bid < 8064) {
        int t = bid - 3456;
        seg = 6 + t / 2304;
        off = (t % 2304) * 1024;
    } else {
        int t = bid - 8064;
        seg = 8 + t / 6144;
        off = (t % 6144) * 1024;
    }
    const float* s = p.s[seg];
    __hip_bfloat16* d = p.d[seg];
    int i = off + threadIdx.x * 4;
    float4 v = *(const float4*)(s + i);
    d[i + 0] = __float2bfloat16(v.x);
    d[i + 1] = __float2bfloat16(v.y);
    d[i + 2] = __float2bfloat16(v.z);
    d[i + 3] = __float2bfloat16(v.w);
}

extern "C" void kernel_launch(void* const* d_in, const int* in_sizes, int n_in,
                              void* d_out, int out_size, void* d_ws, size_t ws_size,
                              hipStream_t stream) {
    const int Bb = 4, S = 2048, E = 768, DFF = 3072;
    const int Nr = Bb * S;  // 8192

    const float* x    = (const float*)d_in[0];
    const float* kv   = (const float*)d_in[1];
    const float* wq_w = (const float*)d_in[2];
    const float* wq_b = (const float*)d_in[3];
    const float* wk_w = (const float*)d_in[4];
    const float* wk_b = (const float*)d_in[5];
    const float* wv_w = (const float*)d_in[6];
    const float* wv_b = (const float*)d_in[7];
    const float* ln1g = (const float*)d_in[8];
    const float* ln1b = (const float*)d_in[9];
    const float* wq2w = (const float*)d_in[10];
    const float* wq2b = (const float*)d_in[11];
    const float* wk2w = (const float*)d_in[12];
    const float* wk2b = (const float*)d_in[13];
    const float* wv2w = (const float*)d_in[14];
    const float* wv2b = (const float*)d_in[15];
    const float* ln2g = (const float*)d_in[16];
    const float* ln2b = (const float*)d_in[17];
    const float* w1   = (const float*)d_in[18];
    const float* b1   = (const float*)d_in[19];
    const float* w2   = (const float*)d_in[20];
    const float* b2   = (const float*)d_in[21];
    const float* ln3g = (const float*)d_in[22];
    const float* ln3b = (const float*)d_in[23];
    float* out = (float*)d_out;

    // ---- workspace (bump allocator, 256B aligned) ~155 MB ----
    char* wsp = (char*)d_ws;
    auto alloc = [&](size_t bytes) {
        char* p = wsp;
        wsp += (bytes + 255) & ~(size_t)255;
        return p;
    };
    const size_t nSE = (size_t)Nr * E;       // 6,291,456
    const size_t nSS = (size_t)Bb * S * S;   // 16,777,216
    __hip_bfloat16* Pb   = (__hip_bfloat16*)alloc(nSS * 2);   // 33.5 MB
    __hip_bfloat16* qb   = (__hip_bfloat16*)alloc(nSE * 2);
    __hip_bfloat16* kb   = (__hip_bfloat16*)alloc(nSE * 2);
    __hip_bfloat16* hffb = Pb;  // MLP hidden overlays Pb+qb+kb (58.7 >= 50.3 MB)
    __hip_bfloat16* vtb  = (__hip_bfloat16*)alloc(nSE * 2);   // V^T [b][E][S]
    __hip_bfloat16* xb   = (__hip_bfloat16*)alloc(nSE * 2);
    __hip_bfloat16* kvb  = (__hip_bfloat16*)alloc(nSE * 2);
    __hip_bfloat16* actb = (__hip_bfloat16*)alloc(nSE * 2);   // residual chain
    __hip_bfloat16* hA   = (__hip_bfloat16*)alloc(nSE * 2);   // split-K partial A
    __hip_bfloat16* hB   = (__hip_bfloat16*)alloc(nSE * 2);   // split-K partial B
    __hip_bfloat16* wqb   = (__hip_bfloat16*)alloc((size_t)E * E * 2);
    __hip_bfloat16* wkb   = (__hip_bfloat16*)alloc((size_t)E * E * 2);
    __hip_bfloat16* wvb   = (__hip_bfloat16*)alloc((size_t)E * E * 2);
    __hip_bfloat16* wq2bm = (__hip_bfloat16*)alloc((size_t)E * E * 2);
    __hip_bfloat16* wk2bm = (__hip_bfloat16*)alloc((size_t)E * E * 2);
    __hip_bfloat16* wv2bm = (__hip_bfloat16*)alloc((size_t)E * E * 2);
    __hip_bfloat16* w1b   = (__hip_bfloat16*)alloc((size_t)DFF * E * 2);
    __hip_bfloat16* w2b   = (__hip_bfloat16*)alloc((size_t)E * DFF * 2);
    float* lsum1 = (float*)alloc((size_t)Nr * 4);
    float* lsum2 = (float*)alloc((size_t)Nr * 4);

    // K2 / V2^T live in d_out used as scratch (exactly 2*nSE*2 bytes = out_size);
    // both are dead before ln3 writes the real output.
    __hip_bfloat16* k2b  = (__hip_bfloat16*)d_out;
    __hip_bfloat16* vtb2 = k2b + nSE;

    const float scale = 1.0f / sqrtf((float)E);
    const dim3 blk(256);
    const dim3 blk5(512);

    // ---- all conversions + lsum zeroing in one launch ----
    CvtPtrs cp;
    cp.s[0] = wq_w; cp.d[0] = wqb;
    cp.s[1] = wk_w; cp.d[1] = wkb;
    cp.s[2] = wv_w; cp.d[2] = wvb;
    cp.s[3] = wq2w; cp.d[3] = wq2bm;
    cp.s[4] = wk2w; cp.d[4] = wk2bm;
    cp.s[5] = wv2w; cp.d[5] = wv2bm;
    cp.s[6] = w1;   cp.d[6] = w1b;
    cp.s[7] = w2;   cp.d[7] = w2b;
    cp.s[8] = x;    cp.d[8] = xb;
    cp.s[9] = kv;   cp.d[9] = kvb;
    cp.zero = lsum1;  // lsum1+lsum2 contiguous (2*Nr floats)
    cvt_all<<<8064 + 12288 + 16, blk, 0, stream>>>(cp);

    // ---- fused projections: Q,K,V(self from xb) + K2,V2(cross from kvb) ----
    {   // 5 z-slices x 96 blocks = 480 blocks (256^2)
        MMArgs a{};
        a.g[0] = {(const bf16_t*)xb,  (const bf16_t*)wqb,   wq_b, qb,   nullptr, 0, 0};
        a.g[1] = {(const bf16_t*)xb,  (const bf16_t*)wkb,   wk_b, kb,   nullptr, 0, 0};
        a.g[2] = {(const bf16_t*)xb,  (const bf16_t*)wvb,   wv_b, vtb,  nullptr, 0, 1};
        a.g[3] = {(const bf16_t*)kvb, (const bf16_t*)wk2bm, wk2b, k2b,  nullptr, 0, 0};
        a.g[4] = {(const bf16_t*)kvb, (const bf16_t*)wv2bm, wv2b, vtb2, nullptr, 0, 1};
        mm8_std<false, false><<<dim3(96, 1, 5), blk5, 0, stream>>>(
            a, Nr, E, E, E, E, 1.f, 3);
    }
    // ---- causal self-attention ----
    {   // causal QK^T + exp: 36 triangle tiles x 4 batches (256^2)
        MMArgs a{};
        for (int b = 0; b < 4; ++b)
            a.g[b] = {(const bf16_t*)qb + (long)b * S * E,
                      (const bf16_t*)kb + (long)b * S * E, nullptr,
                      Pb + (long)b * S * S, lsum1 + b * S, 0, 0};
        mm8_exp<true><<<dim3(36, 1, 4), blk5, 0, stream>>>(a, S, E, E, E, scale, 8);
    }
    {   // causal PV split-K=2 with 128-granular K-clamp (128^2: 768 blocks)
        MMArgs a{};
        for (int b = 0; b < 4; ++b)
            for (int ks = 0; ks < 2; ++ks)
                a.g[b * 2 + ks] = {(const bf16_t*)Pb + (long)b * S * S + ks * 1024,
                                   (const bf16_t*)vtb + (long)b * E * S + ks * 1024,
                                   nullptr, (ks ? hB : hA) + (long)b * S * E,
                                   nullptr, ks * 1024, 0};
        mm4_std<false, true><<<dim3(96, 1, 8), blk5, 0, stream>>>(
            a, S, E, 1024, S, S, 1.f, 6);
    }
    ln_kernel<false, false><<<Nr, blk, 0, stream>>>(
        nullptr, xb, hA, hB, nullptr, lsum1, ln1g, ln1b, nullptr, actb);

    // ---- cross-attention ----
    {   // Q2 projection (128^2: 384 blocks, 1.5 dense rounds at 2/CU)
        MMArgs a{};
        a.g[0] = {(const bf16_t*)actb, (const bf16_t*)wq2bm, wq2b, qb, nullptr, 0, 0};
        mm4_std<false, false><<<dim3(384, 1, 1), blk5, 0, stream>>>(
            a, Nr, E, E, E, E, 1.f, 6);
    }
    {   // full QK^T + exp: 64 tiles x 4 batches (256^2, 1.0 round)
        MMArgs a{};
        for (int b = 0; b < 4; ++b)
            a.g[b] = {(const bf16_t*)qb + (long)b * S * E,
                      (const bf16_t*)k2b + (long)b * S * E, nullptr,
                      Pb + (long)b * S * S, lsum2 + b * S, 0, 0};
        mm8_exp<false><<<dim3(64, 1, 4), blk5, 0, stream>>>(a, S, E, E, E, scale, 8);
    }
    {   // full PV split-K=2, bf16 partials (256^2)
        MMArgs a{};
        for (int b = 0; b < 4; ++b)
            for (int ks = 0; ks < 2; ++ks)
                a.g[b * 2 + ks] = {(const bf16_t*)Pb + (long)b * S * S + ks * 1024,
                                   (const bf16_t*)vtb2 + (long)b * E * S + ks * 1024,
                                   nullptr, (ks ? hB : hA) + (long)b * S * E,
                                   nullptr, 0, 0};
        mm8_std<false, false><<<dim3(24, 1, 8), blk5, 0, stream>>>(
            a, S, E, 1024, S, S, 1.f, 3);
    }
    ln_kernel<false, false><<<Nr, blk, 0, stream>>>(
        nullptr, actb, hA, hB, nullptr, lsum2, ln2g, ln2b, nullptr, actb);

    // ---- MLP ----
    {   // MLP1: fused bias+ReLU (128^2: 1536 blocks = 3.0 perfect rounds)
        MMArgs a{};
        a.g[0] = {(const bf16_t*)actb, (const bf16_t*)w1b, b1, hffb, nullptr, 0, 0};
        mm4_std<true, false><<<dim3(1536, 1, 1), blk5, 0, stream>>>(
            a, Nr, DFF, E, E, E, 1.f, 24);
    }
    {   // MLP2 split-K=2, bf16 partials; bias+ReLU applied in ln3 (256^2)
        MMArgs a{};
        a.g[0] = {(const bf16_t*)hffb, (const bf16_t*)w2b, nullptr, hA, nullptr, 0, 0};
        a.g[1] = {(const bf16_t*)hffb + 1536, (const bf16_t*)w2b + 1536, nullptr,
                  hB, nullptr, 0, 0};
        mm8_std<false, false><<<dim3(96, 1, 2), blk5, 0, stream>>>(
            a, Nr, E, 1536, DFF, DFF, 1.f, 3);
    }
    ln_kernel<true, false><<<Nr, blk, 0, stream>>>(
        nullptr, actb, hA, hB, b2, nullptr, ln3g, ln3b, out, nullptr);
}